// Round 10
// baseline (233.227 us; speedup 1.0000x reference)
//
#include <hip/hip_runtime.h>
#include <stdint.h>

#define V_DIM 32000
#define M_TOT 4096      // B*S
#define NF 128          // 2*n_freq
#define NC 256          // channels
#define BM 16           // M-tile: one MFMA fragment high
#define BK 64           // K-step (floats)
#define KSTEPS 500      // V_DIM / BK
#define NSPL 2          // each block reads 16 rows x 64KB CONTIGUOUS
#define SPS 250         // KSTEPS / NSPL, exact
#define THREADS 256

typedef __bf16 bf16x8 __attribute__((ext_vector_type(8)));
typedef float f32x4 __attribute__((ext_vector_type(4)));

__device__ __forceinline__ unsigned short f2bf(float f) {  // RNE (table build)
  unsigned int u = __float_as_uint(f);
  u += 0x7FFFu + ((u >> 16) & 1u);
  return (unsigned short)(u >> 16);
}

// two fp32 -> packed bf16x2 by truncation (1 v_perm); measured safe (absmax 1.0 << 2.96)
__device__ __forceinline__ unsigned int pk2(float lo, float hi) {
  return __builtin_amdgcn_perm(__float_as_uint(hi), __float_as_uint(lo), 0x07060302u);
}

__device__ __forceinline__ void gllA(const float* g, const float* l) {
  __builtin_amdgcn_global_load_lds(
      (const __attribute__((address_space(1))) void*)g,
      (__attribute__((address_space(3))) void*)l, 16, 0, 0);
}
__device__ __forceinline__ void gllB(const unsigned short* g, const unsigned short* l) {
  __builtin_amdgcn_global_load_lds(
      (const __attribute__((address_space(1))) void*)g,
      (__attribute__((address_space(3))) void*)l, 16, 0, 0);
}

// ---------------- Stage 0: DFT table, staging order for BM=16/BK=64 blocks ----------
// Per step: 1024 chunks of 16B staged linearly; chunk r = col*8 + ps (col 0..127,
// phys slot ps 0..7). Baked B swizzle: logical slot ls = ps ^ (col & 7).
//   elem e -> T_log[col][step*64 + ls*8 + e]
//   T_log[f][v] = cos(2pi(f+1)v/V) (f<64), -sin(2pi(f-63)v/V) (f>=64)
// gemm1 reads with the same XOR -> content automatically correct (rule 21).
__global__ __launch_bounds__(256) void build_table(unsigned short* __restrict__ T) {
  int id = blockIdx.x * 256 + threadIdx.x;
  if (id >= 1024 * KSTEPS) return;              // 512000
  int step = id >> 10;
  int r = id & 1023;
  int col = r >> 3;
  int ps = r & 7;
  int ls = ps ^ (col & 7);
  int k = (col < 64) ? (col + 1) : (col - 63);
  bool is_cos = (col < 64);
  int vb = step * 64 + ls * 8;
  const float w0 = 6.283185307179586f / (float)V_DIM;
  union { unsigned short us[8]; int4 v; } u;
  #pragma unroll
  for (int e = 0; e < 8; ++e) {
    int mm = (k * (vb + e)) % V_DIM;            // exact range reduction
    float s, cc;
    __sincosf((float)mm * w0, &s, &cc);
    u.us[e] = f2bf(is_cos ? cc : -s);
  }
  *reinterpret_cast<int4*>(T + (size_t)id * 8) = u.v;
}

// ---------------- Stage 1: P[ks] = x_rows @ T^T, x read CONTIGUOUSLY ----------------
// Each block: 16 rows, k-range [ks*16000, +16000) -> 16 sequential 64KB streams.
__global__ __launch_bounds__(THREADS) void gemm1(
    const float* __restrict__ x, const unsigned short* __restrict__ T,
    float* __restrict__ P) {
  __shared__ __align__(16) float As[2][BM * BK];          // 4 KB each
  __shared__ __align__(16) unsigned short Bs[2][NF * BK]; // 16 KB each

  const int b = blockIdx.x;
  const int ks = b & 1;                 // k-half
  const int mt = b >> 1;                // 0..255
  const int m0 = mt * BM;
  const int step0 = ks * SPS;           // absolute step base

  const int t = threadIdx.x;
  const int lane = t & 63, wave = t >> 6;
  const int kgl = lane >> 4, rl = lane & 15;

  // A staging: 1 gllA per wave per step. Wave w covers rows w*4..w*4+3;
  // lane: row = w*4 + (lane>>4), phys slot p = lane&15 (16B slots of a 256B row).
  // Baked 4-bit XOR swizzle rot(row) = ((row&7)<<1) | (row>>3) via SOURCE address:
  // LDS[row][p] = x[row][p ^ rot(row)]  (read uses the same XOR -> self-inverse).
  const int arow = wave * 4 + (lane >> 4);
  const int als = (lane & 15) ^ (((arow & 7) << 1) | (arow >> 3));
  const float* asrc = x + (size_t)(m0 + arow) * V_DIM + (size_t)step0 * BK + als * 4;
  // B staging: 4 gllB per wave per step, chunk id = q*256 + wave*64 + lane, linear.
  const unsigned short* bsrc = T + (size_t)step0 * 8192 + (size_t)(wave * 64 + lane) * 8;

  f32x4 acc[2];
  acc[0] = (f32x4){0.f, 0.f, 0.f, 0.f};
  acc[1] = (f32x4){0.f, 0.f, 0.f, 0.f};

  auto stage = [&](int s, int buf) {          // 5 vmem instr per wave
    gllA(asrc + (size_t)s * BK, &As[buf][wave * 256]);
    const unsigned short* ts = bsrc + (size_t)s * 8192;
    #pragma unroll
    for (int q = 0; q < 4; ++q)
      gllB(ts + q * 2048, &Bs[buf][q * 2048 + wave * 512]);
  };

  stage(0, 0);
  __syncthreads();

  // lane-constant read-address pieces
  const int arot = ((rl & 7) << 1) | (rl >> 3);   // rot(row) for row = rl
  const int bxor = rl & 7;                        // col&7 for col = wave*32+nf*16+rl

  for (int s = 0; s < SPS; ++s) {
    const int cur = s & 1, nxt = cur ^ 1;
    if (s + 1 < SPS) stage(s + 1, nxt);     // in flight across the compute

    #pragma unroll
    for (int kk = 0; kk < 2; ++kk) {
      // B fragments: col*64 ushorts, slot (kk*4+kgl) ^ (col&7)
      bf16x8 bfr[2];
      #pragma unroll
      for (int nf = 0; nf < 2; ++nf) {
        int col = wave * 32 + nf * 16 + rl;
        int ps = (kk * 4 + kgl) ^ bxor;
        bfr[nf] = *reinterpret_cast<const bf16x8*>(&Bs[cur][col * 64 + ps * 8]);
      }
      // A fragment: row = rl, logical slots s0, s0+1 -> phys via XOR rot
      int s0 = kk * 8 + kgl * 2;
      float4 lo = *reinterpret_cast<const float4*>(
          &As[cur][rl * 64 + ((s0 ^ arot) * 4)]);
      float4 hi = *reinterpret_cast<const float4*>(
          &As[cur][rl * 64 + (((s0 + 1) ^ arot) * 4)]);
      union { uint4 u; bf16x8 v; } a8;
      a8.u.x = pk2(lo.x, lo.y); a8.u.y = pk2(lo.z, lo.w);
      a8.u.z = pk2(hi.x, hi.y); a8.u.w = pk2(hi.z, hi.w);
      #pragma unroll
      for (int nf = 0; nf < 2; ++nf)
        acc[nf] = __builtin_amdgcn_mfma_f32_16x16x32_bf16(
            a8.v, bfr[nf], acc[nf], 0, 0, 0);
    }
    __syncthreads();   // buf nxt staged, buf cur reads complete
  }

  // ---- epilogue: partial [16 x 128] tile for this k-half
  float* Pp = P + ((size_t)ks * M_TOT + m0) * NF;
  const int r0 = (lane >> 4) * 4;
  const int col16 = lane & 15;
  #pragma unroll
  for (int nf = 0; nf < 2; ++nf)
    #pragma unroll
    for (int q = 0; q < 4; ++q)
      Pp[(size_t)(r0 + q) * NF + wave * 32 + nf * 16 + col16] = acc[nf][q];
}

// ---------------- Stage 2: out = (sum_s P[s]) @ W^T ----------------
__global__ __launch_bounds__(256) void gemm2(
    const float* __restrict__ P, const float* __restrict__ W,
    float* __restrict__ out, int NS) {
  __shared__ __align__(16) float Xr[8][NF];
  const int mb = blockIdx.x * 8;
  const int t = threadIdx.x;

  #pragma unroll
  for (int i = 0; i < 4; ++i) {
    int idx = t + i * 256;           // 8 rows x 128 freqs
    int r = idx >> 7, f = idx & 127;
    float s = 0.f;
    for (int sp = 0; sp < NS; ++sp)
      s += P[((size_t)sp * M_TOT + mb + r) * NF + f];
    Xr[r][f] = s;
  }
  __syncthreads();

  const float4* Wr = reinterpret_cast<const float4*>(W + (size_t)t * NF);
  float accr[8];
  #pragma unroll
  for (int r = 0; r < 8; ++r) accr[r] = 0.f;

  for (int f4 = 0; f4 < NF / 4; ++f4) {
    float4 w = Wr[f4];
    #pragma unroll
    for (int r = 0; r < 8; ++r) {
      float4 xv = *reinterpret_cast<const float4*>(&Xr[r][f4 * 4]);
      accr[r] += xv.x * w.x + xv.y * w.y + xv.z * w.z + xv.w * w.w;
    }
  }
  #pragma unroll
  for (int r = 0; r < 8; ++r)
    out[(size_t)(mb + r) * NC + t] = accr[r];
}

extern "C" void kernel_launch(void* const* d_in, const int* in_sizes, int n_in,
                              void* d_out, int out_size, void* d_ws, size_t ws_size,
                              hipStream_t stream) {
  const float* x = (const float*)d_in[0];
  const float* w = (const float*)d_in[1];
  float* out = (float*)d_out;

  unsigned short* T = (unsigned short*)d_ws;
  const size_t t_bytes = (size_t)NF * V_DIM * sizeof(unsigned short); // 8,192,000
  float* P = (float*)((char*)d_ws + t_bytes);
  // ws need: 8 MB (T) + 2 * 2 MiB (P) = 12 MB.

  build_table<<<dim3(2000), dim3(256), 0, stream>>>(T);
  gemm1<<<dim3((M_TOT / BM) * NSPL), dim3(THREADS), 0, stream>>>(x, T, P);
  gemm2<<<dim3(M_TOT / 8), dim3(256), 0, stream>>>(P, w, out, NSPL);
}

// Round 11
// 176.835 us; speedup vs baseline: 1.3189x; 1.3189x over previous
//
#include <hip/hip_runtime.h>
#include <stdint.h>

#define V_DIM 32000
#define M_TOT 4096      // B*S
#define NF 128          // 2*n_freq
#define NC 256          // channels
#define BM 64           // M-tile
#define NSPL 8          // k-splits: 512 blocks = 2/CU, XCD-pinned
#define THREADS 256
#define ROWSTR 264      // ushorts per A-row: 256 data + 8 pad (bank rotation)

typedef __bf16 bf16x8 __attribute__((ext_vector_type(8)));
typedef float f32x4 __attribute__((ext_vector_type(4)));

__device__ __forceinline__ unsigned short f2bf(float f) {  // RNE (table build)
  unsigned int u = __float_as_uint(f);
  u += 0x7FFFu + ((u >> 16) & 1u);
  return (unsigned short)(u >> 16);
}

// two fp32 -> packed bf16x2 by truncation (1 v_perm); measured safe (absmax 1.0 << 2.96)
__device__ __forceinline__ unsigned int pk2(float lo, float hi) {
  return __builtin_amdgcn_perm(__float_as_uint(hi), __float_as_uint(lo), 0x07060302u);
}

// ---------------- Stage 0: DFT basis in B-FRAGMENT order (R4-verified layout) --------
// elem addr = (((c2*4) + kgl)*128 + col)*8 + e ; c2 = 32-float k-chunk (0..999)
//   value = T_log[col][c2*32 + kgl*8 + e]
//   T_log[f][v] = cos(2pi(f+1)v/V) f<64 ; -sin(2pi(f-63)v/V) f>=64
// gemm1 lane (kgl,rl) reads its bf16x8 B-fragment as ONE contiguous 16B L2-hit load.
__global__ __launch_bounds__(256) void build_table(unsigned short* __restrict__ T) {
  int id = blockIdx.x * 256 + threadIdx.x;   // slot id
  if (id >= 512000) return;
  int n = id & 127;                          // col
  int g = id >> 7;
  int kgl = g & 3;
  int c2 = g >> 2;                           // 0..999
  int vb = c2 * 32 + kgl * 8;
  int k = (n < 64) ? (n + 1) : (n - 63);
  bool is_cos = (n < 64);
  const float w0 = 6.283185307179586f / (float)V_DIM;
  union { unsigned short us[8]; uint4 v; } u;
  #pragma unroll
  for (int e = 0; e < 8; ++e) {
    int m = (k * (vb + e)) % V_DIM;          // exact range reduction
    float s, cc;
    __sincosf((float)m * w0, &s, &cc);
    u.us[e] = f2bf(is_cos ? cc : -s);
  }
  *reinterpret_cast<uint4*>(T + (size_t)id * 8) = u.v;
}

// ---------------- Stage 1: P[ks] = x_tile @ T^T -------------------------------------
// Big-granule staging: per stage, 1KB contiguous per row (256 floats), then 8 MFMA
// substeps (BK=32) with NO intermediate barriers. B direct from L2 (fragment order).
__global__ __launch_bounds__(THREADS) void gemm1(
    const float* __restrict__ x, const unsigned short* __restrict__ T,
    float* __restrict__ P) {
  __shared__ __align__(16) unsigned short As[2][BM * ROWSTR];  // 33792 B per buf

  const int b = blockIdx.x;
  const int ks = b & 7;                 // XCD j hosts ks=j only -> T slice L2-hot
  const int mt = b >> 3;                // 0..63
  const int m0 = mt * BM;
  const int kf0 = ks * 4000;            // float offset of this block's k-range
  const int kc0 = ks * 125;             // 32-chunk index base

  const int t = threadIdx.x;
  const int lane = t & 63, wave = t >> 6;
  const int kgl = lane >> 4, rl = lane & 15;

  // A staging: thread -> (row = t>>2, seg = t&3); 16 float4 = 256B contiguous.
  const int row_t = t >> 2, seg = t & 3;
  const float* xa = x + (size_t)(m0 + row_t) * V_DIM + kf0 + seg * 64;
  const float* xtail = x + (size_t)(m0 + row_t) * V_DIM + kf0 + 3840 + seg * 40;
  const int wb_full = row_t * ROWSTR + seg * 64;   // ushort idx (seg*8 slots)
  const int wb_tail = row_t * ROWSTR + seg * 40;   // tail: seg*5 slots

  // B fragment base: col = wave*32 + rl (+ nf*16); per c2 advance 4096 ushorts
  const unsigned short* tb = T + ((size_t)(kc0 * 4 + kgl) * 128 + wave * 32 + rl) * 8;

  f32x4 acc[4][2];
  #pragma unroll
  for (int a = 0; a < 4; ++a)
    #pragma unroll
    for (int c = 0; c < 2; ++c) acc[a][c] = (f32x4){0.f, 0.f, 0.f, 0.f};

  float4 xv[16];   // statically indexed after unroll (rule 20)

  auto packw = [&](int buf, int nslots, int wbase) {
    #pragma unroll
    for (int i = 0; i < 8; ++i) {
      if (i < nslots) {
        uint4 w;
        w.x = pk2(xv[2 * i].x, xv[2 * i].y);
        w.y = pk2(xv[2 * i].z, xv[2 * i].w);
        w.z = pk2(xv[2 * i + 1].x, xv[2 * i + 1].y);
        w.w = pk2(xv[2 * i + 1].z, xv[2 * i + 1].w);
        *reinterpret_cast<uint4*>(&As[buf][wbase + i * 8]) = w;
      }
    }
  };

  // ---- prologue: stage 0 into buf0
  {
    #pragma unroll
    for (int i = 0; i < 16; ++i)
      xv[i] = *reinterpret_cast<const float4*>(xa + i * 4);
    packw(0, 8, wb_full);
    __syncthreads();
  }

#define COMPUTE(NSUB, ST)                                                     \
  {                                                                           \
    const unsigned short* tbs = tb + (size_t)((ST) * 8) * 4096;               \
    bf16x8 bc0 = *reinterpret_cast<const bf16x8*>(tbs);                       \
    bf16x8 bc1 = *reinterpret_cast<const bf16x8*>(tbs + 128);                 \
    _Pragma("unroll")                                                         \
    for (int kk = 0; kk < (NSUB); ++kk) {                                     \
      bf16x8 bn0, bn1;                                                        \
      if (kk + 1 < (NSUB)) {                                                  \
        bn0 = *reinterpret_cast<const bf16x8*>(tbs + (kk + 1) * 4096);        \
        bn1 = *reinterpret_cast<const bf16x8*>(tbs + (kk + 1) * 4096 + 128);  \
      }                                                                       \
      _Pragma("unroll")                                                       \
      for (int mf = 0; mf < 4; ++mf) {                                        \
        bf16x8 av = *reinterpret_cast<const bf16x8*>(                         \
            &As[cur][(mf * 16 + rl) * ROWSTR + (kk * 4 + kgl) * 8]);          \
        acc[mf][0] = __builtin_amdgcn_mfma_f32_16x16x32_bf16(                 \
            av, bc0, acc[mf][0], 0, 0, 0);                                    \
        acc[mf][1] = __builtin_amdgcn_mfma_f32_16x16x32_bf16(                 \
            av, bc1, acc[mf][1], 0, 0, 0);                                    \
      }                                                                       \
      bc0 = bn0; bc1 = bn1;                                                   \
    }                                                                         \
  }

  // ---- 16 stages: 15 full (8 substeps) + 1 tail (5 substeps)
  for (int st = 0; st < 16; ++st) {
    const int cur = st & 1, nxt = cur ^ 1;

    // 1) issue next stage's A loads (in flight across this stage's MFMAs)
    if (st + 1 < 15) {
      const float* p = xa + (size_t)(st + 1) * 256;
      #pragma unroll
      for (int i = 0; i < 16; ++i)
        xv[i] = *reinterpret_cast<const float4*>(p + i * 4);
    } else if (st + 1 == 15) {
      #pragma unroll
      for (int i = 0; i < 10; ++i)
        xv[i] = *reinterpret_cast<const float4*>(xtail + i * 4);
    }

    // 2) compute all substeps of this stage (no barriers inside)
    if (st < 15) COMPUTE(8, st) else COMPUTE(5, st)

    // 3) consume the loads: pack -> ds_write into nxt (vmcnt wait lands here)
    if (st + 1 < 15)       packw(nxt, 8, wb_full);
    else if (st + 1 == 15) packw(nxt, 5, wb_tail);

    __syncthreads();
  }
#undef COMPUTE

  // ---- epilogue: partial [64 x 128] tile for this k-split
  float* Pp = P + ((size_t)ks * M_TOT + m0) * NF;
  const int r0 = (lane >> 4) * 4;
  const int col16 = lane & 15;
  #pragma unroll
  for (int mf = 0; mf < 4; ++mf)
    #pragma unroll
    for (int nf = 0; nf < 2; ++nf)
      #pragma unroll
      for (int q = 0; q < 4; ++q)
        Pp[(size_t)(mf * 16 + r0 + q) * NF + wave * 32 + nf * 16 + col16] =
            acc[mf][nf][q];
}

// ---------------- Stage 2: out = (sum_s P[s]) @ W^T ----------------
__global__ __launch_bounds__(256) void gemm2(
    const float* __restrict__ P, const float* __restrict__ W,
    float* __restrict__ out, int NS) {
  __shared__ __align__(16) float Xr[8][NF];
  const int mb = blockIdx.x * 8;
  const int t = threadIdx.x;

  #pragma unroll
  for (int i = 0; i < 4; ++i) {
    int idx = t + i * 256;           // 8 rows x 128 freqs
    int r = idx >> 7, f = idx & 127;
    float s = 0.f;
    for (int sp = 0; sp < NS; ++sp)
      s += P[((size_t)sp * M_TOT + mb + r) * NF + f];
    Xr[r][f] = s;
  }
  __syncthreads();

  const float4* Wr = reinterpret_cast<const float4*>(W + (size_t)t * NF);
  float accr[8];
  #pragma unroll
  for (int r = 0; r < 8; ++r) accr[r] = 0.f;

  for (int f4 = 0; f4 < NF / 4; ++f4) {
    float4 w = Wr[f4];
    #pragma unroll
    for (int r = 0; r < 8; ++r) {
      float4 xv = *reinterpret_cast<const float4*>(&Xr[r][f4 * 4]);
      accr[r] += xv.x * w.x + xv.y * w.y + xv.z * w.z + xv.w * w.w;
    }
  }
  #pragma unroll
  for (int r = 0; r < 8; ++r)
    out[(size_t)(mb + r) * NC + t] = accr[r];
}

extern "C" void kernel_launch(void* const* d_in, const int* in_sizes, int n_in,
                              void* d_out, int out_size, void* d_ws, size_t ws_size,
                              hipStream_t stream) {
  const float* x = (const float*)d_in[0];
  const float* w = (const float*)d_in[1];
  float* out = (float*)d_out;

  unsigned short* T = (unsigned short*)d_ws;
  const size_t t_bytes = (size_t)NF * V_DIM * sizeof(unsigned short); // 8,192,000
  float* P = (float*)((char*)d_ws + t_bytes);
  // ws need: 8 MB (T) + 8 * 2 MiB (P) = 24 MB (proven available).

  build_table<<<dim3(2000), dim3(256), 0, stream>>>(T);
  gemm1<<<dim3(64 * NSPL), dim3(THREADS), 0, stream>>>(x, T, P);
  gemm2<<<dim3(M_TOT / 8), dim3(256), 0, stream>>>(P, w, out, NSPL);
}